// Round 9
// baseline (259.670 us; speedup 1.0000x reference)
//
#include <hip/hip_runtime.h>
#include <hip/hip_bf16.h>
#include <math.h>
#include <stdint.h>

// Problem constants: B=2, S=2048, D=1024, H=16, DK=64
constexpr int Bb = 2, Ss = 2048, Dd = 1024, Hh = 16;
constexpr int Mm = Bb * Ss;  // 4096 (GEMM M)
constexpr int Nn = Dd;       // 1024
constexpr int Kk = Dd;       // 1024
// fold 1/sqrt(DK) and log2(e) into Q so the softmax uses exp2
constexpr float QSCALE = 0.125f * 1.44269504088896340736f;

typedef unsigned short ushort_t;
typedef __attribute__((ext_vector_type(8))) short bf16x8;   // A/B frag (4 VGPRs)
typedef __attribute__((ext_vector_type(4))) float f32x4;    // 16x16 C/D frag

#if __has_builtin(__builtin_amdgcn_exp2f)
#define EXP2F(x) __builtin_amdgcn_exp2f(x)
#else
#define EXP2F(x) exp2f(x)
#endif

__device__ __forceinline__ ushort_t f2bf(float f) {  // round-to-nearest-even
  union { float f; unsigned u; } v; v.f = f;
  return (ushort_t)((v.u + 0x7fff + ((v.u >> 16) & 1)) >> 16);
}

// async global->LDS, 16B per lane; LDS dest is wave-uniform base + lane*16
__device__ __forceinline__ void load16_lds(const void* g, void* l) {
  __builtin_amdgcn_global_load_lds(
      (const __attribute__((address_space(1))) void*)(uintptr_t)g,
      (__attribute__((address_space(3))) void*)(uint32_t)(uintptr_t)l, 16, 0, 0);
}

// ---------------------------------------------------------------------------
// W [K][N] fp32 -> Wt [N][K] bf16  (B-operand wants K-contiguous rows)
// ---------------------------------------------------------------------------
__global__ __launch_bounds__(256) void transpose_w(
    const float* __restrict__ Wq, const float* __restrict__ Wk,
    const float* __restrict__ Wv, const float* __restrict__ Wo,
    ushort_t* __restrict__ Wt) {
  const int z = blockIdx.z;
  const float* W = (z == 0) ? Wq : (z == 1) ? Wk : (z == 2) ? Wv : Wo;
  ushort_t* out = Wt + (size_t)z * Kk * Nn;
  __shared__ float t[64][65];
  const int tid = threadIdx.x;
  const int n0 = blockIdx.x * 64, k0 = blockIdx.y * 64;
  const int lr = tid >> 4, lc = (tid & 15) * 4;
#pragma unroll
  for (int i = 0; i < 4; i++) {
    const int r = lr + i * 16;
    const float4 v = *(const float4*)(W + (size_t)(k0 + r) * Nn + n0 + lc);
    t[r][lc] = v.x; t[r][lc + 1] = v.y; t[r][lc + 2] = v.z; t[r][lc + 3] = v.w;
  }
  __syncthreads();
  const int n = tid >> 2, kc = (tid & 3) * 16;
  ushort_t tmp[16];
#pragma unroll
  for (int j = 0; j < 16; j++) tmp[j] = f2bf(t[kc + j][n]);
  ushort_t* op = out + (size_t)(n0 + n) * Kk + k0 + kc;
  ((uint4*)op)[0] = ((uint4*)tmp)[0];
  ((uint4*)op)[1] = ((uint4*)tmp)[1];
}

// ---------------------------------------------------------------------------
// Vp [B*S][D] bf16 -> Vt [B][D][S] bf16  (PV A-operand wants V^T rows)
// ---------------------------------------------------------------------------
__global__ __launch_bounds__(256) void transpose_v(
    const ushort_t* __restrict__ Vp, ushort_t* __restrict__ Vt) {
  __shared__ ushort_t t[64][68];
  const int tid = threadIdx.x;
  const int s0 = blockIdx.x * 64, h = blockIdx.y, b = blockIdx.z;
  const int lr = tid >> 4, lc = (tid & 15) * 4;
#pragma unroll
  for (int i = 0; i < 4; i++) {
    const int r = lr + i * 16;
    const ushort4 v =
        *(const ushort4*)(Vp + (size_t)(b * Ss + s0 + r) * Dd + h * 64 + lc);
    *(ushort4*)&t[r][lc] = v;
  }
  __syncthreads();
  const int d = tid >> 2, sc = (tid & 3) * 16;
  ushort_t tmp[16];
#pragma unroll
  for (int j = 0; j < 16; j++) tmp[j] = t[sc + j][d];
  ushort_t* op = Vt + ((size_t)b * Dd + h * 64 + d) * Ss + s0 + sc;
  ((uint4*)op)[0] = ((uint4*)tmp)[0];
  ((uint4*)op)[1] = ((uint4*)tmp)[1];
}

// ---------------------------------------------------------------------------
// bf16 MFMA GEMM, m97 recipe: BM=128, BK=32, 16x16x32 MFMA (r7 measured-best
// core, reverted from 32x32 which cost +11us).
// A_FP32 variant fuses the fp32->bf16 convert into A-staging: float4 loads ->
// f2bf -> ds_write_b64 into a PADDED As (row stride 40 el = 80B: 16B-aligned
// rows, 2-way banks on frag reads = free). B stays global_load_lds (bf16,
// unpadded 64B rows). Kills the convert dispatch + 100MB of HBM round-trip.
// ---------------------------------------------------------------------------
template <int BN, bool OUT_BF16, bool A_FP32>
__global__ __launch_bounds__(256) void gemm_mfma(
    const void* __restrict__ A0, const void* __restrict__ A1,
    const void* __restrict__ A2, const ushort_t* __restrict__ Wbase,
    size_t w_stride, const float* __restrict__ bias0,
    const float* __restrict__ bias1, const float* __restrict__ bias2,
    void* __restrict__ Cbase, size_t c_stride, float scale_z0) {
  constexpr int BM = 128, BK = 32;
  constexpr int ASTR = A_FP32 ? 40 : 32;     // padded rows when VGPR-staged
  constexpr int WM = (BN == 128) ? 64 : 32;  // wave tile
  constexpr int MT_ = WM / 16, NT_ = 4;      // WN = 64 always
  __shared__ ushort_t As[BM * ASTR];
  __shared__ ushort_t Bs[BN * BK];
  const int tid = threadIdx.x, lane = tid & 63, wid = tid >> 6;
  const int z = blockIdx.z;
  const void* Av = (z == 0) ? A0 : (z == 1) ? A1 : A2;
  const ushort_t* Wt = Wbase + (size_t)z * w_stride;
  const float* bias = (z == 0) ? bias0 : (z == 1) ? bias1 : bias2;
  const float sc = (z == 0) ? scale_z0 : 1.0f;
  const int m0 = blockIdx.y * BM, n0 = blockIdx.x * BN;
  const int wm = (BN == 128) ? (wid >> 1) * 64 : wid * 32;
  const int wn = (BN == 128) ? (wid & 1) * 64 : 0;
  const int quad = lane >> 4, r16 = lane & 15;
  const int srow = lane >> 2;        // DMA staging: 16 rows/inst
  const int scol = (lane & 3) * 8;   // 4 lanes x 16B per 64B row

  f32x4 acc[MT_][NT_];
#pragma unroll
  for (int m = 0; m < MT_; m++)
#pragma unroll
    for (int n = 0; n < NT_; n++) acc[m][n] = f32x4{0.f, 0.f, 0.f, 0.f};

  for (int k0 = 0; k0 < Kk; k0 += BK) {
    __syncthreads();
    if (A_FP32) {
      const float* A = (const float*)Av;
#pragma unroll
      for (int i = 0; i < 4; i++) {  // 4 insts x 256 thr = 128 rows x 8 chunks
        const int idx = i * 256 + tid;
        const int row = idx >> 3, c = idx & 7;
        const float4 v4 =
            *(const float4*)(A + (size_t)(m0 + row) * Kk + k0 + c * 4);
        ushort4 o;
        o.x = f2bf(v4.x); o.y = f2bf(v4.y); o.z = f2bf(v4.z); o.w = f2bf(v4.w);
        *(ushort4*)(As + row * ASTR + c * 4) = o;
      }
    } else {
      const ushort_t* A = (const ushort_t*)Av;
#pragma unroll
      for (int i = 0; i < BM / 64; i++) {
        const int I = wid * (BM / 64) + i;
        load16_lds(A + (size_t)(m0 + I * 16 + srow) * Kk + k0 + scol,
                   As + I * 512);
      }
    }
#pragma unroll
    for (int i = 0; i < BN / 64; i++) {
      const int I = wid * (BN / 64) + i;
      load16_lds(Wt + (size_t)(n0 + I * 16 + srow) * Kk + k0 + scol, Bs + I * 512);
    }
    __syncthreads();
    bf16x8 af[MT_], bfr[NT_];
#pragma unroll
    for (int m = 0; m < MT_; m++)
      af[m] = *(const bf16x8*)(As + (wm + m * 16 + r16) * ASTR + quad * 8);
#pragma unroll
    for (int n = 0; n < NT_; n++)
      bfr[n] = *(const bf16x8*)(Bs + (wn + n * 16 + r16) * BK + quad * 8);
#pragma unroll
    for (int m = 0; m < MT_; m++)
#pragma unroll
      for (int n = 0; n < NT_; n++)
        acc[m][n] =
            __builtin_amdgcn_mfma_f32_16x16x32_bf16(af[m], bfr[n], acc[m][n], 0, 0, 0);
  }

  // epilogue: C/D layout col=lane&15, row=quad*4+reg
#pragma unroll
  for (int m = 0; m < MT_; m++) {
#pragma unroll
    for (int n = 0; n < NT_; n++) {
      const int gc = n0 + wn + n * 16 + r16;
      const float bv = bias[gc];
#pragma unroll
      for (int r = 0; r < 4; r++) {
        const int gr = m0 + wm + m * 16 + quad * 4 + r;
        const float v = (acc[m][n][r] + bv) * sc;
        if (OUT_BF16)
          ((ushort_t*)Cbase)[(size_t)z * c_stride + (size_t)gr * Nn + gc] = f2bf(v);
        else
          ((float*)Cbase)[(size_t)z * c_stride + (size_t)gr * Nn + gc] = v;
      }
    }
  }
}

// ---------------------------------------------------------------------------
// MFMA flash attention v3 (measured best: ~64 us).
// 64-row Q-tiles, 256 threads, each wave owns 16 qrows. Latency-bound on the
// barrier-drained staging loop; wave count (16/CU at 4 blocks) hides it.
// ---------------------------------------------------------------------------
__global__ __launch_bounds__(256) void flash_mfma(
    const ushort_t* __restrict__ Qp, const ushort_t* __restrict__ Kp,
    const ushort_t* __restrict__ Vt, ushort_t* __restrict__ Xp) {
  __shared__ ushort_t Ks[64 * 64];   // [key][d], chunk-swizzled
  __shared__ ushort_t Vts[64 * 64];  // [d][key], chunk-swizzled
  __shared__ ushort_t Ps[64 * 72];   // [qrow][key], stride 72
  const int tid = threadIdx.x, lane = tid & 63, wid = tid >> 6;
  const int qt = blockIdx.x, h = blockIdx.y, b = blockIdx.z;
  const int quad = lane >> 4, r16 = lane & 15;
  const int row8 = lane >> 3;                       // staging row in 8-row chunk
  const int colsw = ((lane & 7) ^ (row8 & 7)) * 8;  // swizzled source col (u16)
  const int swz = r16 & 7;                          // read-side swizzle key

  const int qrow = wid * 16 + r16;  // this lane's qrow within the 64-tile
  const ushort_t* Qg = Qp + ((size_t)(b * Ss + qt * 64)) * Dd + h * 64;
  const ushort_t* Kg = Kp + ((size_t)b * Ss) * Dd + h * 64;
  const ushort_t* Vg = Vt + ((size_t)b * Dd + h * 64) * Ss;  // rows d, stride S

  // Q fragments in registers (B-operand: n=qrow, k=d contiguous)
  bf16x8 qf[2];
#pragma unroll
  for (int ks = 0; ks < 2; ks++)
    qf[ks] = *(const bf16x8*)(Qg + (size_t)qrow * Dd + ks * 32 + quad * 8);

  f32x4 acc[4];  // Ot: m=d-tile(4), n=qrow
  float rs = 0.f;
#pragma unroll
  for (int mt = 0; mt < 4; mt++) acc[mt] = f32x4{0.f, 0.f, 0.f, 0.f};

  for (int kt = 0; kt < Ss / 64; kt++) {
    __syncthreads();  // prev iter done reading Ks/Vts
#pragma unroll
    for (int i = 0; i < 2; i++) {
      const int I = wid * 2 + i;
      load16_lds(Kg + (size_t)(kt * 64 + I * 8 + row8) * Dd + colsw, Ks + I * 512);
      load16_lds(Vg + (size_t)(I * 8 + row8) * Ss + kt * 64 + colsw, Vts + I * 512);
    }
    __syncthreads();

    // St[key][qrow] = K Q^T for this wave's 16 qrows x 64 keys
    f32x4 sacc[4];
#pragma unroll
    for (int mm = 0; mm < 4; mm++) sacc[mm] = f32x4{0.f, 0.f, 0.f, 0.f};
#pragma unroll
    for (int ks = 0; ks < 2; ks++) {
      const int ko = ((ks * 4 + quad) ^ swz) * 8;
      bf16x8 kf[4];
#pragma unroll
      for (int mm = 0; mm < 4; mm++)
        kf[mm] = *(const bf16x8*)(Ks + (mm * 16 + r16) * 64 + ko);
#pragma unroll
      for (int mm = 0; mm < 4; mm++)
        sacc[mm] = __builtin_amdgcn_mfma_f32_16x16x32_bf16(
            kf[mm], qf[ks], sacc[mm], 0, 0, 0);
    }

    // p = exp2(s); row-sum partials; packed 8B P write
#pragma unroll
    for (int mm = 0; mm < 4; mm++) {
      float p0 = EXP2F(sacc[mm][0]), p1 = EXP2F(sacc[mm][1]);
      float p2 = EXP2F(sacc[mm][2]), p3 = EXP2F(sacc[mm][3]);
      rs += (p0 + p1) + (p2 + p3);
      union { __hip_bfloat162 hh; unsigned u; } lo, hi;
      lo.hh = __float22bfloat162_rn(make_float2(p0, p1));
      hi.hh = __float22bfloat162_rn(make_float2(p2, p3));
      *(uint2*)(Ps + qrow * 72 + mm * 16 + quad * 4) = make_uint2(lo.u, hi.u);
    }
    // P rows wave-private: in-wave lgkmcnt ordering suffices, no barrier.

    // Ot[d][qrow] += V^T P^T
#pragma unroll
    for (int ks = 0; ks < 2; ks++) {
      const int ko = ((ks * 4 + quad) ^ swz) * 8;
      bf16x8 vf[4];
#pragma unroll
      for (int mt = 0; mt < 4; mt++)
        vf[mt] = *(const bf16x8*)(Vts + (mt * 16 + r16) * 64 + ko);
      const bf16x8 pf = *(const bf16x8*)(Ps + qrow * 72 + ks * 32 + quad * 8);
#pragma unroll
      for (int mt = 0; mt < 4; mt++)
        acc[mt] = __builtin_amdgcn_mfma_f32_16x16x32_bf16(
            vf[mt], pf, acc[mt], 0, 0, 0);
    }
  }

  // full row sum: combine the 4 key-quads (lanes with same r16)
  rs += __shfl_xor(rs, 16, 64);
  rs += __shfl_xor(rs, 32, 64);
  const float inv = 1.0f / rs;

  // write X: Ot C-layout: d = mt*16+quad*4+r (consecutive r), qrow = r16
#pragma unroll
  for (int mt = 0; mt < 4; mt++) {
    ushort4 o;
    o.x = f2bf(acc[mt][0] * inv);
    o.y = f2bf(acc[mt][1] * inv);
    o.z = f2bf(acc[mt][2] * inv);
    o.w = f2bf(acc[mt][3] * inv);
    *(ushort4*)(Xp + (size_t)(b * Ss + qt * 64 + qrow) * Dd +
                h * 64 + mt * 16 + quad * 4) = o;
  }
}

// ---------------------------------------------------------------------------
extern "C" void kernel_launch(void* const* d_in, const int* in_sizes, int n_in,
                              void* d_out, int out_size, void* d_ws,
                              size_t ws_size, hipStream_t stream) {
  const float* q  = (const float*)d_in[0];
  const float* k  = (const float*)d_in[1];
  const float* v  = (const float*)d_in[2];
  const float* Wq = (const float*)d_in[3];
  const float* bq = (const float*)d_in[4];
  const float* Wk = (const float*)d_in[5];
  const float* bk = (const float*)d_in[6];
  const float* Wv = (const float*)d_in[7];
  const float* bv = (const float*)d_in[8];
  const float* Wo = (const float*)d_in[9];
  const float* bo = (const float*)d_in[10];

  ushort_t* ws = (ushort_t*)d_ws;
  const size_t MD = (size_t)Mm * Kk;  // 4,194,304
  const size_t KN = (size_t)Kk * Nn;  // 1,048,576
  ushort_t* Wt   = ws;                // 4*KN   transposed weights
  ushort_t* QKVp = ws + 4 * KN;       // 3*MD   Q,K,V projections
  ushort_t* Vtp  = QKVp + 3 * MD;     // MD     V^T per head
  ushort_t* Xp   = Vtp + MD;          // MD     attention output (bf16)
  // total = 4*KN + 5*MD = 8 MB + 42 MB = 50 MB workspace

  transpose_w<<<dim3(16, 16, 4), 256, 0, stream>>>(Wq, Wk, Wv, Wo, Wt);
  gemm_mfma<128, true, true><<<dim3(Nn / 128, Mm / 128, 3), 256, 0, stream>>>(
      q, k, v, Wt, KN, bq, bk, bv, QKVp, MD, QSCALE);
  transpose_v<<<dim3(Ss / 64, Hh, Bb), 256, 0, stream>>>(QKVp + 2 * MD, Vtp);
  flash_mfma<<<dim3(Ss / 64, Hh, Bb), 256, 0, stream>>>(QKVp, QKVp + MD, Vtp, Xp);
  gemm_mfma<64, false, false><<<dim3(Nn / 64, Mm / 128, 1), 256, 0, stream>>>(
      Xp, Xp, Xp, Wt + 3 * KN, 0, bo, bo, bo, d_out, 0, 1.0f);
}

// Round 10
// 239.705 us; speedup vs baseline: 1.0833x; 1.0833x over previous
//
#include <hip/hip_runtime.h>
#include <hip/hip_bf16.h>
#include <math.h>
#include <stdint.h>

// Problem constants: B=2, S=2048, D=1024, H=16, DK=64
constexpr int Bb = 2, Ss = 2048, Dd = 1024, Hh = 16;
constexpr int Mm = Bb * Ss;  // 4096 (GEMM M)
constexpr int Nn = Dd;       // 1024
constexpr int Kk = Dd;       // 1024
// fold 1/sqrt(DK) and log2(e) into Q so the softmax uses exp2
constexpr float QSCALE = 0.125f * 1.44269504088896340736f;

typedef unsigned short ushort_t;
typedef __attribute__((ext_vector_type(8))) short bf16x8;   // A/B frag (4 VGPRs)
typedef __attribute__((ext_vector_type(4))) float f32x4;    // 16x16 C/D frag

#if __has_builtin(__builtin_amdgcn_exp2f)
#define EXP2F(x) __builtin_amdgcn_exp2f(x)
#else
#define EXP2F(x) exp2f(x)
#endif

__device__ __forceinline__ ushort_t f2bf(float f) {  // round-to-nearest-even
  union { float f; unsigned u; } v; v.f = f;
  return (ushort_t)((v.u + 0x7fff + ((v.u >> 16) & 1)) >> 16);
}

// async global->LDS, 16B per lane; LDS dest is wave-uniform base + lane*16
__device__ __forceinline__ void load16_lds(const void* g, void* l) {
  __builtin_amdgcn_global_load_lds(
      (const __attribute__((address_space(1))) void*)(uintptr_t)g,
      (__attribute__((address_space(3))) void*)(uint32_t)(uintptr_t)l, 16, 0, 0);
}

// ---------------------------------------------------------------------------
// Merged prep pass (one dispatch):
//  blocks [0, 12288): fp32->bf16 convert of q,k,v  (z = bid/4096)
//  blocks [12288, 13312): W [K][N] fp32 -> Wt [N][K] bf16 transpose
// Independent workloads; merging saves a launch + inter-dispatch gap.
// ---------------------------------------------------------------------------
__global__ __launch_bounds__(256) void prep(
    const float* __restrict__ q, const float* __restrict__ k,
    const float* __restrict__ v, ushort_t* __restrict__ qkvb,
    const float* __restrict__ Wq, const float* __restrict__ Wk,
    const float* __restrict__ Wv, const float* __restrict__ Wo,
    ushort_t* __restrict__ Wt) {
  const int bid = blockIdx.x;
  const int tid = threadIdx.x;
  if (bid < 12288) {  // ---- convert q/k/v ----
    const int z = bid >> 12, xi = bid & 4095;
    const float* src = (z == 0) ? q : (z == 1) ? k : v;
    ushort_t* dst = qkvb + (size_t)z * Mm * Kk;
    const size_t idx = ((size_t)xi * 256 + tid) * 4;
    const float4 val = *(const float4*)(src + idx);
    ushort4 o;
    o.x = f2bf(val.x); o.y = f2bf(val.y); o.z = f2bf(val.z); o.w = f2bf(val.w);
    *(ushort4*)(dst + idx) = o;
    return;
  }
  // ---- transpose weights ----
  const int bid2 = bid - 12288;
  const int z = bid2 >> 8, rem = bid2 & 255;
  const float* W = (z == 0) ? Wq : (z == 1) ? Wk : (z == 2) ? Wv : Wo;
  ushort_t* out = Wt + (size_t)z * Kk * Nn;
  __shared__ float t[64][65];
  const int n0 = (rem & 15) * 64, k0 = (rem >> 4) * 64;
  const int lr = tid >> 4, lc = (tid & 15) * 4;
#pragma unroll
  for (int i = 0; i < 4; i++) {
    const int r = lr + i * 16;
    const float4 vv = *(const float4*)(W + (size_t)(k0 + r) * Nn + n0 + lc);
    t[r][lc] = vv.x; t[r][lc + 1] = vv.y; t[r][lc + 2] = vv.z; t[r][lc + 3] = vv.w;
  }
  __syncthreads();
  const int n = tid >> 2, kc = (tid & 3) * 16;
  ushort_t tmp[16];
#pragma unroll
  for (int j = 0; j < 16; j++) tmp[j] = f2bf(t[kc + j][n]);
  ushort_t* op = out + (size_t)(n0 + n) * Kk + k0 + kc;
  ((uint4*)op)[0] = ((uint4*)tmp)[0];
  ((uint4*)op)[1] = ((uint4*)tmp)[1];
}

// ---------------------------------------------------------------------------
// Vp [B*S][D] bf16 -> Vt [B][D][S] bf16  (PV A-operand wants V^T rows)
// ---------------------------------------------------------------------------
__global__ __launch_bounds__(256) void transpose_v(
    const ushort_t* __restrict__ Vp, ushort_t* __restrict__ Vt) {
  __shared__ ushort_t t[64][68];
  const int tid = threadIdx.x;
  const int s0 = blockIdx.x * 64, h = blockIdx.y, b = blockIdx.z;
  const int lr = tid >> 4, lc = (tid & 15) * 4;
#pragma unroll
  for (int i = 0; i < 4; i++) {
    const int r = lr + i * 16;
    const ushort4 v =
        *(const ushort4*)(Vp + (size_t)(b * Ss + s0 + r) * Dd + h * 64 + lc);
    *(ushort4*)&t[r][lc] = v;
  }
  __syncthreads();
  const int d = tid >> 2, sc = (tid & 3) * 16;
  ushort_t tmp[16];
#pragma unroll
  for (int j = 0; j < 16; j++) tmp[j] = t[sc + j][d];
  ushort_t* op = Vt + ((size_t)b * Dd + h * 64 + d) * Ss + s0 + sc;
  ((uint4*)op)[0] = ((uint4*)tmp)[0];
  ((uint4*)op)[1] = ((uint4*)tmp)[1];
}

// ---------------------------------------------------------------------------
// bf16 MFMA GEMM, m97 recipe: BM=128, BK=32, global_load_lds width=16,
// 16x16x32 MFMA — the r7 measured-best core (32x32 variant cost +11us; fused
// fp32-A staging cost +16us via doubled HBM re-fetch — both reverted).
// A [M][K] bf16, Wt [N][K] bf16 (pre-transposed), out = (A@W + bias)*scale.
// ---------------------------------------------------------------------------
template <int BN, bool OUT_BF16>
__global__ __launch_bounds__(256) void gemm_mfma(
    const ushort_t* __restrict__ Abase, size_t a_stride,
    const ushort_t* __restrict__ Wbase, size_t w_stride,
    const float* __restrict__ bias0, const float* __restrict__ bias1,
    const float* __restrict__ bias2, void* __restrict__ Cbase, size_t c_stride,
    float scale_z0) {
  constexpr int BM = 128, BK = 32;
  constexpr int WM = (BN == 128) ? 64 : 32;  // wave tile
  constexpr int MT_ = WM / 16, NT_ = 4;      // WN = 64 always
  __shared__ ushort_t As[BM * BK];
  __shared__ ushort_t Bs[BN * BK];
  const int tid = threadIdx.x, lane = tid & 63, wid = tid >> 6;
  const int z = blockIdx.z;
  const ushort_t* A = Abase + (size_t)z * a_stride;
  const ushort_t* Wt = Wbase + (size_t)z * w_stride;
  const float* bias = (z == 0) ? bias0 : (z == 1) ? bias1 : bias2;
  const float sc = (z == 0) ? scale_z0 : 1.0f;
  const int m0 = blockIdx.y * BM, n0 = blockIdx.x * BN;
  const int wm = (BN == 128) ? (wid >> 1) * 64 : wid * 32;
  const int wn = (BN == 128) ? (wid & 1) * 64 : 0;
  const int quad = lane >> 4, r16 = lane & 15;
  const int srow = lane >> 2;        // staging: 16 rows/inst
  const int scol = (lane & 3) * 8;   // 4 lanes x 16B per 64B row

  f32x4 acc[MT_][NT_];
#pragma unroll
  for (int m = 0; m < MT_; m++)
#pragma unroll
    for (int n = 0; n < NT_; n++) acc[m][n] = f32x4{0.f, 0.f, 0.f, 0.f};

  for (int k0 = 0; k0 < Kk; k0 += BK) {
    __syncthreads();
#pragma unroll
    for (int i = 0; i < BM / 64; i++) {
      const int I = wid * (BM / 64) + i;
      load16_lds(A + (size_t)(m0 + I * 16 + srow) * Kk + k0 + scol, As + I * 512);
    }
#pragma unroll
    for (int i = 0; i < BN / 64; i++) {
      const int I = wid * (BN / 64) + i;
      load16_lds(Wt + (size_t)(n0 + I * 16 + srow) * Kk + k0 + scol, Bs + I * 512);
    }
    __syncthreads();
    bf16x8 af[MT_], bfr[NT_];
#pragma unroll
    for (int m = 0; m < MT_; m++)
      af[m] = *(const bf16x8*)(As + (wm + m * 16 + r16) * BK + quad * 8);
#pragma unroll
    for (int n = 0; n < NT_; n++)
      bfr[n] = *(const bf16x8*)(Bs + (wn + n * 16 + r16) * BK + quad * 8);
#pragma unroll
    for (int m = 0; m < MT_; m++)
#pragma unroll
      for (int n = 0; n < NT_; n++)
        acc[m][n] =
            __builtin_amdgcn_mfma_f32_16x16x32_bf16(af[m], bfr[n], acc[m][n], 0, 0, 0);
  }

  // epilogue: C/D layout col=lane&15, row=quad*4+reg
#pragma unroll
  for (int m = 0; m < MT_; m++) {
#pragma unroll
    for (int n = 0; n < NT_; n++) {
      const int gc = n0 + wn + n * 16 + r16;
      const float bv = bias[gc];
#pragma unroll
      for (int r = 0; r < 4; r++) {
        const int gr = m0 + wm + m * 16 + quad * 4 + r;
        const float v = (acc[m][n][r] + bv) * sc;
        if (OUT_BF16)
          ((ushort_t*)Cbase)[(size_t)z * c_stride + (size_t)gr * Nn + gc] = f2bf(v);
        else
          ((float*)Cbase)[(size_t)z * c_stride + (size_t)gr * Nn + gc] = v;
      }
    }
  }
}

// ---------------------------------------------------------------------------
// MFMA flash attention v3 (measured best: ~64 us).
// 64-row Q-tiles, 256 threads, each wave owns 16 qrows. Latency-bound on the
// barrier-drained staging loop; wave count (16/CU at 4 blocks) hides it.
// ---------------------------------------------------------------------------
__global__ __launch_bounds__(256) void flash_mfma(
    const ushort_t* __restrict__ Qp, const ushort_t* __restrict__ Kp,
    const ushort_t* __restrict__ Vt, ushort_t* __restrict__ Xp) {
  __shared__ ushort_t Ks[64 * 64];   // [key][d], chunk-swizzled
  __shared__ ushort_t Vts[64 * 64];  // [d][key], chunk-swizzled
  __shared__ ushort_t Ps[64 * 72];   // [qrow][key], stride 72
  const int tid = threadIdx.x, lane = tid & 63, wid = tid >> 6;
  const int qt = blockIdx.x, h = blockIdx.y, b = blockIdx.z;
  const int quad = lane >> 4, r16 = lane & 15;
  const int row8 = lane >> 3;                       // staging row in 8-row chunk
  const int colsw = ((lane & 7) ^ (row8 & 7)) * 8;  // swizzled source col (u16)
  const int swz = r16 & 7;                          // read-side swizzle key

  const int qrow = wid * 16 + r16;  // this lane's qrow within the 64-tile
  const ushort_t* Qg = Qp + ((size_t)(b * Ss + qt * 64)) * Dd + h * 64;
  const ushort_t* Kg = Kp + ((size_t)b * Ss) * Dd + h * 64;
  const ushort_t* Vg = Vt + ((size_t)b * Dd + h * 64) * Ss;  // rows d, stride S

  // Q fragments in registers (B-operand: n=qrow, k=d contiguous)
  bf16x8 qf[2];
#pragma unroll
  for (int ks = 0; ks < 2; ks++)
    qf[ks] = *(const bf16x8*)(Qg + (size_t)qrow * Dd + ks * 32 + quad * 8);

  f32x4 acc[4];  // Ot: m=d-tile(4), n=qrow
  float rs = 0.f;
#pragma unroll
  for (int mt = 0; mt < 4; mt++) acc[mt] = f32x4{0.f, 0.f, 0.f, 0.f};

  for (int kt = 0; kt < Ss / 64; kt++) {
    __syncthreads();  // prev iter done reading Ks/Vts
#pragma unroll
    for (int i = 0; i < 2; i++) {
      const int I = wid * 2 + i;
      load16_lds(Kg + (size_t)(kt * 64 + I * 8 + row8) * Dd + colsw, Ks + I * 512);
      load16_lds(Vg + (size_t)(I * 8 + row8) * Ss + kt * 64 + colsw, Vts + I * 512);
    }
    __syncthreads();

    // St[key][qrow] = K Q^T for this wave's 16 qrows x 64 keys
    f32x4 sacc[4];
#pragma unroll
    for (int mm = 0; mm < 4; mm++) sacc[mm] = f32x4{0.f, 0.f, 0.f, 0.f};
#pragma unroll
    for (int ks = 0; ks < 2; ks++) {
      const int ko = ((ks * 4 + quad) ^ swz) * 8;
      bf16x8 kf[4];
#pragma unroll
      for (int mm = 0; mm < 4; mm++)
        kf[mm] = *(const bf16x8*)(Ks + (mm * 16 + r16) * 64 + ko);
#pragma unroll
      for (int mm = 0; mm < 4; mm++)
        sacc[mm] = __builtin_amdgcn_mfma_f32_16x16x32_bf16(
            kf[mm], qf[ks], sacc[mm], 0, 0, 0);
    }

    // p = exp2(s); row-sum partials; packed 8B P write
#pragma unroll
    for (int mm = 0; mm < 4; mm++) {
      float p0 = EXP2F(sacc[mm][0]), p1 = EXP2F(sacc[mm][1]);
      float p2 = EXP2F(sacc[mm][2]), p3 = EXP2F(sacc[mm][3]);
      rs += (p0 + p1) + (p2 + p3);
      union { __hip_bfloat162 hh; unsigned u; } lo, hi;
      lo.hh = __float22bfloat162_rn(make_float2(p0, p1));
      hi.hh = __float22bfloat162_rn(make_float2(p2, p3));
      *(uint2*)(Ps + qrow * 72 + mm * 16 + quad * 4) = make_uint2(lo.u, hi.u);
    }
    // P rows wave-private: in-wave lgkmcnt ordering suffices, no barrier.

    // Ot[d][qrow] += V^T P^T
#pragma unroll
    for (int ks = 0; ks < 2; ks++) {
      const int ko = ((ks * 4 + quad) ^ swz) * 8;
      bf16x8 vf[4];
#pragma unroll
      for (int mt = 0; mt < 4; mt++)
        vf[mt] = *(const bf16x8*)(Vts + (mt * 16 + r16) * 64 + ko);
      const bf16x8 pf = *(const bf16x8*)(Ps + qrow * 72 + ks * 32 + quad * 8);
#pragma unroll
      for (int mt = 0; mt < 4; mt++)
        acc[mt] = __builtin_amdgcn_mfma_f32_16x16x32_bf16(
            vf[mt], pf, acc[mt], 0, 0, 0);
    }
  }

  // full row sum: combine the 4 key-quads (lanes with same r16)
  rs += __shfl_xor(rs, 16, 64);
  rs += __shfl_xor(rs, 32, 64);
  const float inv = 1.0f / rs;

  // write X: Ot C-layout: d = mt*16+quad*4+r (consecutive r), qrow = r16
#pragma unroll
  for (int mt = 0; mt < 4; mt++) {
    ushort4 o;
    o.x = f2bf(acc[mt][0] * inv);
    o.y = f2bf(acc[mt][1] * inv);
    o.z = f2bf(acc[mt][2] * inv);
    o.w = f2bf(acc[mt][3] * inv);
    *(ushort4*)(Xp + (size_t)(b * Ss + qt * 64 + qrow) * Dd +
                h * 64 + mt * 16 + quad * 4) = o;
  }
}

// ---------------------------------------------------------------------------
extern "C" void kernel_launch(void* const* d_in, const int* in_sizes, int n_in,
                              void* d_out, int out_size, void* d_ws,
                              size_t ws_size, hipStream_t stream) {
  const float* q  = (const float*)d_in[0];
  const float* k  = (const float*)d_in[1];
  const float* v  = (const float*)d_in[2];
  const float* Wq = (const float*)d_in[3];
  const float* bq = (const float*)d_in[4];
  const float* Wk = (const float*)d_in[5];
  const float* bk = (const float*)d_in[6];
  const float* Wv = (const float*)d_in[7];
  const float* bv = (const float*)d_in[8];
  const float* Wo = (const float*)d_in[9];
  const float* bo = (const float*)d_in[10];

  ushort_t* ws = (ushort_t*)d_ws;
  const size_t MD = (size_t)Mm * Kk;  // 4,194,304
  const size_t KN = (size_t)Kk * Nn;  // 1,048,576
  ushort_t* qkvb = ws;                // 3*MD   bf16 inputs
  ushort_t* Wt   = ws + 3 * MD;       // 4*KN   transposed weights
  ushort_t* QKVp = Wt + 4 * KN;       // 3*MD   Q,K,V projections
  ushort_t* Vtp  = QKVp + 3 * MD;     // MD     V^T per head
  ushort_t* Xp   = qkvb;              // reuse: qkvb dead after QKV GEMMs

  prep<<<dim3(13312), 256, 0, stream>>>(q, k, v, qkvb, Wq, Wk, Wv, Wo, Wt);
  gemm_mfma<128, true><<<dim3(Nn / 128, Mm / 128, 3), 256, 0, stream>>>(
      qkvb, MD, Wt, KN, bq, bk, bv, QKVp, MD, QSCALE);
  transpose_v<<<dim3(Ss / 64, Hh, Bb), 256, 0, stream>>>(QKVp + 2 * MD, Vtp);
  flash_mfma<<<dim3(Ss / 64, Hh, Bb), 256, 0, stream>>>(QKVp, QKVp + MD, Vtp, Xp);
  gemm_mfma<64, false><<<dim3(Nn / 64, Mm / 128, 1), 256, 0, stream>>>(
      Xp, 0, Wt + 3 * KN, 0, bo, bo, bo, d_out, 0, 1.0f);
}